// Round 1
// baseline (51.514 us; speedup 1.0000x reference)
//
#include <hip/hip_runtime.h>
#include <cmath>

#ifndef M_PI
#define M_PI 3.14159265358979323846
#endif

namespace {

constexpr int VDIM = 512;
constexpr int RDIM = 1024;
constexpr int NPIX = VDIM * RDIM;

// ---- Batcher odd-even mergesort network, arbitrary n (compile-time) ----
struct Net {
  int cnt;
  int a[700];
  int b[700];
};

constexpr Net make_net(int n) {
  Net net{};
  net.cnt = 0;
  for (int p = 1; p < n; p *= 2)
    for (int k = p; k >= 1; k /= 2)
      for (int j = k % p; j + k < n; j += 2 * k)
        for (int i = 0; i < k && i + j + k < n; ++i)
          if ((i + j) / (2 * p) == (i + j + k) / (2 * p)) {
            net.a[net.cnt] = i + j;
            net.b[net.cnt] = i + j + k;
            ++net.cnt;
          }
  return net;
}

constexpr Net NET48 = make_net(48);
constexpr Net NET36 = make_net(36);

// ---- ring offsets (row-major like np.argwhere; order irrelevant for rank) ----
struct Offs { int dy[144]; int dx[144]; };
constexpr Offs make_offs() {
  Offs o{};
  int c = 0;
  for (int dy = -6; dy <= 6; ++dy)
    for (int dx = -6; dx <= 6; ++dx)
      if (!(dy >= -2 && dy <= 2 && dx >= -2 && dx <= 2)) {
        o.dy[c] = dy;
        o.dx[c] = dx;
        ++c;
      }
  return o;
}
constexpr Offs OFF = make_offs();

}  // namespace

__device__ __forceinline__ void cx_desc(float& x, float& y) {
  float mx = fmaxf(x, y);
  float mn = fminf(x, y);
  x = mx;
  y = mn;
}

__device__ __forceinline__ void sort48(float (&v)[48]) {
#pragma unroll
  for (int c = 0; c < NET48.cnt; ++c) cx_desc(v[NET48.a[c]], v[NET48.b[c]]);
}

__device__ __forceinline__ void sort36(float (&v)[36]) {
#pragma unroll
  for (int c = 0; c < NET36.cnt; ++c) cx_desc(v[NET36.a[c]], v[NET36.b[c]]);
}

template <int BASE>
__device__ __forceinline__ void load_chunk(const float* __restrict__ in, int r, int c,
                                           float (&t)[48]) {
#pragma unroll
  for (int i = 0; i < 48; ++i) {
    int rr = (r + OFF.dy[BASE + i]) & (VDIM - 1);
    int cc = (c + OFF.dx[BASE + i]) & (RDIM - 1);
    t[i] = in[rr * RDIM + cc];
  }
}

__global__ __launch_bounds__(256) void cfar_os_kernel(const float* __restrict__ in,
                                                      float* __restrict__ out, float alpha) {
  int tid = blockIdx.x * blockDim.x + threadIdx.x;
  int r = tid >> 10;           // row 0..511
  int c = tid & (RDIM - 1);    // col 0..1023

  float A[48], B[48];
  load_chunk<0>(in, r, c, A);
  sort48(A);
  load_chunk<48>(in, r, c, B);
  sort48(B);

  // top-36 multiset of A ∪ B  (both sorted descending)
  float S[36];
#pragma unroll
  for (int i = 0; i < 36; ++i) S[i] = fmaxf(A[i], B[35 - i]);
  sort36(S);  // restore sorted order for the next merge

  load_chunk<96>(in, r, c, B);
  sort48(B);

  // answer = min of top-36 of S ∪ B = 36th largest of all 144
  float m = fmaxf(S[0], B[35]);
#pragma unroll
  for (int i = 1; i < 36; ++i) m = fminf(m, fmaxf(S[i], B[35 - i]));

  out[tid] = alpha * m;
}

// ---- host-side faithful port of the reference ALPHA computation ----
static double log_factorial_port(int n_) {
  double n = n_ + 1.0;
  if (n < 9.0) {
    double f = 1.0;
    for (int i = 2; i <= (int)(n + 0.5); ++i) f *= (double)i;
    return log(f);
  }
  return 0.5 * (log(2.0 * M_PI) - log(n)) +
         n * (log(n + 1.0 / (12.0 * n - 1.0 / (10.0 * n))) - 1.0);
}

static double cfar_fun(int k, int n, double t, double pfa) {
  double s = 0.0;
  for (int i = n; i > n - k; --i) s += log((double)i + t);
  return log_factorial_port(n) - log_factorial_port(n - k) - s - log(pfa);
}

static float compute_alpha() {
  double lo = 1.0, hi = 1e32;
  for (int it = 0; it < 300; ++it) {
    double mid = 0.5 * (lo + hi);
    if (cfar_fun(108, 144, mid, 1e-5) > 0.0)
      lo = mid;
    else
      hi = mid;
  }
  return (float)(0.5 * (lo + hi));
}

static const float g_alpha = compute_alpha();

extern "C" void kernel_launch(void* const* d_in, const int* in_sizes, int n_in,
                              void* d_out, int out_size, void* d_ws, size_t ws_size,
                              hipStream_t stream) {
  const float* in = (const float*)d_in[0];
  float* out = (float*)d_out;
  dim3 grid(NPIX / 256), block(256);
  hipLaunchKernelGGL(cfar_os_kernel, grid, block, 0, stream, in, out, g_alpha);
}

// Round 2
// 42.918 us; speedup vs baseline: 1.2003x; 1.2003x over previous
//
#include <hip/hip_runtime.h>
#include <cmath>

#ifndef M_PI
#define M_PI 3.14159265358979323846
#endif

namespace {

constexpr int VDIM = 512;
constexpr int RDIM = 1024;

constexpr int TY = 4;            // block tile rows
constexpr int TX = 64;           // block tile cols (one wave per row)
constexpr int TR = TY + 12;      // staged rows  (16)
constexpr int TC = TX + 12;      // staged cols  (76)
constexpr int STRIDE = TC;

// ---- Batcher odd-even mergesort network, arbitrary n (compile-time) ----
struct Net {
  int cnt;
  int a[400];
  int b[400];
};

constexpr Net make_net(int n) {
  Net net{};
  net.cnt = 0;
  for (int p = 1; p < n; p *= 2)
    for (int k = p; k >= 1; k /= 2)
      for (int j = k % p; j + k < n; j += 2 * k)
        for (int i = 0; i < k && i + j + k < n; ++i)
          if ((i + j) / (2 * p) == (i + j + k) / (2 * p)) {
            net.a[net.cnt] = i + j;
            net.b[net.cnt] = i + j + k;
            ++net.cnt;
          }
  return net;
}

// Bitonic merge network for 36 elements (descending), built as the tail of a
// 64-wide bitonic merger whose front 28 slots are virtual +inf pads (pads
// always win the max and never move, so their comparators are elided).
constexpr Net make_bitonic36() {
  Net net{};
  net.cnt = 0;
  for (int d = 32; d >= 1; d >>= 1)
    for (int i = 28; i < 64; ++i)
      if (((i & d) == 0) && (i + d) < 64) {
        net.a[net.cnt] = i - 28;
        net.b[net.cnt] = i + d - 28;
        ++net.cnt;
      }
  return net;
}

constexpr Net NET24 = make_net(24);
constexpr Net BIT36 = make_bitonic36();

// ---- ring offsets as LDS element offsets relative to window top-left ----
struct Offs { int o[144]; };
constexpr Offs make_offs() {
  Offs f{};
  int c = 0;
  for (int dy = -6; dy <= 6; ++dy)
    for (int dx = -6; dx <= 6; ++dx)
      if (!(dy >= -2 && dy <= 2 && dx >= -2 && dx <= 2)) {
        f.o[c] = (dy + 6) * STRIDE + (dx + 6);
        ++c;
      }
  return f;
}
constexpr Offs OFF = make_offs();

}  // namespace

__device__ __forceinline__ void cx_desc(float& x, float& y) {
  float mx = fmaxf(x, y);
  float mn = fminf(x, y);
  x = mx;
  y = mn;
}

__device__ __forceinline__ void sort24(float (&v)[24]) {
#pragma unroll
  for (int c = 0; c < NET24.cnt; ++c) cx_desc(v[NET24.a[c]], v[NET24.b[c]]);
}

__device__ __forceinline__ void bitonic36(float (&v)[36]) {
#pragma unroll
  for (int c = 0; c < BIT36.cnt; ++c) cx_desc(v[BIT36.a[c]], v[BIT36.b[c]]);
}

__global__ __launch_bounds__(256, 4) void cfar_os_kernel(const float* __restrict__ in,
                                                         float* __restrict__ out, float alpha) {
  __shared__ float tile[TR * TC];

  const int tx = threadIdx.x;        // 0..63
  const int ty = threadIdx.y;        // 0..3
  const int t = ty * TX + tx;
  const int r0 = blockIdx.y * TY;
  const int c0 = blockIdx.x * TX;

  // ---- stage (TY+12) x (TX+12) tile with circular wrap ----
#pragma unroll
  for (int e = t; e < TR * TC; e += 256) {
    int rr = e / STRIDE;
    int cc = e - rr * STRIDE;
    int gr = (r0 + rr - 6) & (VDIM - 1);
    int gc = (c0 + cc - 6) & (RDIM - 1);
    tile[e] = in[gr * RDIM + gc];
  }
  __syncthreads();

  const int tb = ty * STRIDE + tx;   // window top-left for this pixel

  float S[36], C[24];

  // chunk 0: initialize running top-36 (pad tail with -inf)
#pragma unroll
  for (int i = 0; i < 24; ++i) C[i] = tile[tb + OFF.o[i]];
  sort24(C);
#pragma unroll
  for (int i = 0; i < 24; ++i) S[i] = C[i];
#pragma unroll
  for (int i = 24; i < 36; ++i) S[i] = -INFINITY;

  // chunks 1..5: fold 24 new cells into the running sorted top-36
#pragma unroll
  for (int ch = 1; ch < 6; ++ch) {
#pragma unroll
    for (int i = 0; i < 24; ++i) C[i] = tile[tb + OFF.o[ch * 24 + i]];
    sort24(C);
    // top-36 of (S desc ∪ C desc): S[i] = max(S[i], C_asc[i-12]) for i>=12.
    // Result is max(descending, ascending) => bitonic; re-sort with BIT36.
#pragma unroll
    for (int i = 12; i < 36; ++i) S[i] = fmaxf(S[i], C[35 - i]);
    bitonic36(S);
  }

  out[(r0 + ty) * RDIM + (c0 + tx)] = alpha * S[35];
}

// ---- host-side faithful port of the reference ALPHA computation ----
static double log_factorial_port(int n_) {
  double n = n_ + 1.0;
  if (n < 9.0) {
    double f = 1.0;
    for (int i = 2; i <= (int)(n + 0.5); ++i) f *= (double)i;
    return log(f);
  }
  return 0.5 * (log(2.0 * M_PI) - log(n)) +
         n * (log(n + 1.0 / (12.0 * n - 1.0 / (10.0 * n))) - 1.0);
}

static double cfar_fun(int k, int n, double t, double pfa) {
  double s = 0.0;
  for (int i = n; i > n - k; --i) s += log((double)i + t);
  return log_factorial_port(n) - log_factorial_port(n - k) - s - log(pfa);
}

static float compute_alpha() {
  double lo = 1.0, hi = 1e32;
  for (int it = 0; it < 300; ++it) {
    double mid = 0.5 * (lo + hi);
    if (cfar_fun(108, 144, mid, 1e-5) > 0.0)
      lo = mid;
    else
      hi = mid;
  }
  return (float)(0.5 * (lo + hi));
}

static const float g_alpha = compute_alpha();

extern "C" void kernel_launch(void* const* d_in, const int* in_sizes, int n_in,
                              void* d_out, int out_size, void* d_ws, size_t ws_size,
                              hipStream_t stream) {
  const float* in = (const float*)d_in[0];
  float* out = (float*)d_out;
  dim3 block(TX, TY);
  dim3 grid(RDIM / TX, VDIM / TY);
  hipLaunchKernelGGL(cfar_os_kernel, grid, block, 0, stream, in, out, g_alpha);
}

// Round 3
// 34.101 us; speedup vs baseline: 1.5106x; 1.2585x over previous
//
#include <hip/hip_runtime.h>
#include <cmath>

#ifndef M_PI
#define M_PI 3.14159265358979323846
#endif

namespace {

constexpr int VDIM = 512;
constexpr int RDIM = 1024;
constexpr int TX = 256;          // pixels per block (one output row)
constexpr int COLS = TX + 12;    // staged columns (268)

struct Net {
  int cnt;
  int a[96];
  int b[96];
};

// Batcher odd-even mergesort (arbitrary n) — descending with max-at-low CE.
constexpr Net make_net(int n) {
  Net net{};
  net.cnt = 0;
  for (int p = 1; p < n; p *= 2)
    for (int k = p; k >= 1; k /= 2)
      for (int j = k % p; j + k < n; j += 2 * k)
        for (int i = 0; i < k && i + j + k < n; ++i)
          if ((i + j) / (2 * p) == (i + j + k) / (2 * p)) {
            net.a[net.cnt] = i + j;
            net.b[net.cnt] = i + j + k;
            ++net.cnt;
          }
  return net;
}

// Descending sorter for a BITONIC input of length n: front-pad to pow2 with
// virtual +inf (pads always keep max at the lower index -> elided).
constexpr Net make_bitonic_desc(int n) {
  int P = 1;
  while (P < n) P *= 2;
  int F = P - n;
  Net net{};
  net.cnt = 0;
  for (int d = P / 2; d >= 1; d /= 2)
    for (int i = F; i + d < P; ++i)
      if ((i & d) == 0) {
        net.a[net.cnt] = i - F;
        net.b[net.cnt] = i - F + d;
        ++net.cnt;
      }
  return net;
}

constexpr Net NET8 = make_net(8);
constexpr Net NET5 = make_net(5);
constexpr Net B13 = make_bitonic_desc(13);
constexpr Net B16 = make_bitonic_desc(16);
constexpr Net B26 = make_bitonic_desc(26);
constexpr Net B32 = make_bitonic_desc(32);
constexpr Net B36 = make_bitonic_desc(36);

}  // namespace

__device__ __forceinline__ void cx_desc(float& x, float& y) {
  float mx = fmaxf(x, y);
  float mn = fminf(x, y);
  x = mx;
  y = mn;
}

#define DEF_APPLY(NAME, NET, L)                                      \
  __device__ __forceinline__ void NAME(float(&v)[L]) {               \
    _Pragma("unroll") for (int c = 0; c < NET.cnt; ++c)              \
        cx_desc(v[NET.a[c]], v[NET.b[c]]);                           \
  }

DEF_APPLY(net8, NET8, 8)
DEF_APPLY(net5, NET5, 5)
DEF_APPLY(b13, B13, 13)
DEF_APPLY(b16, B16, 16)
DEF_APPLY(b26, B26, 26)
DEF_APPLY(b32, B32, 32)
DEF_APPLY(b36, B36, 36)

// ---- cooperative column presort: sorted gap-8 and full-13 into LDS ----
__device__ __forceinline__ void col_task(const float* __restrict__ in, int r0, int c0,
                                         int cc, float* __restrict__ SF,
                                         float* __restrict__ SG) {
  const int gc = (c0 + cc - 6) & (RDIM - 1);
  float v[13];
#pragma unroll
  for (int dy = 0; dy < 13; ++dy) {
    int gr = (r0 + dy - 6) & (VDIM - 1);
    v[dy] = in[gr * RDIM + gc];
  }
  float g[8] = {v[0], v[1], v[2], v[3], v[9], v[10], v[11], v[12]};
  net8(g);
  float m[5] = {v[4], v[5], v[6], v[7], v[8]};
  net5(m);
#pragma unroll
  for (int p = 0; p < 8; ++p) SG[p * COLS + cc] = g[p];
  // merge sorted-8 (desc) + sorted-5 (asc) -> bitonic 13 -> sorted-13 desc
  float f[13];
#pragma unroll
  for (int p = 0; p < 8; ++p) f[p] = g[p];
  f[8] = m[4];
  f[9] = m[3];
  f[10] = m[2];
  f[11] = m[1];
  f[12] = m[0];
  b13(f);
#pragma unroll
  for (int p = 0; p < 13; ++p) SF[p * COLS + cc] = f[p];
}

// load two sorted-13 columns (desc + asc) and merge -> sorted 26 desc
__device__ __forceinline__ void merge26(const float* __restrict__ SF, int cd, int ca,
                                        float (&v)[26]) {
#pragma unroll
  for (int j = 0; j < 13; ++j) v[j] = SF[j * COLS + cd];
#pragma unroll
  for (int j = 0; j < 13; ++j) v[13 + j] = SF[(12 - j) * COLS + ca];
  b26(v);
}

__global__ __launch_bounds__(256, 2) void cfar_os_kernel(const float* __restrict__ in,
                                                         float* __restrict__ out,
                                                         float alpha) {
  __shared__ float SF[13 * COLS];
  __shared__ float SG[8 * COLS];

  const int t = threadIdx.x;
  const int r0 = blockIdx.y;
  const int c0 = blockIdx.x * TX;

  col_task(in, r0, c0, t, SF, SG);
  if (t % 21 == 0) {
    int e = t / 21;
    if (e < COLS - TX) col_task(in, r0, c0, TX + e, SF, SG);
  }
  __syncthreads();

  // ---- B-side: full cols dx=3..6 (cc = t+9..12) + all 5 gap cols ----
  float ta[26], tb[26];
  merge26(SF, t + 9, t + 10, ta);
  merge26(SF, t + 11, t + 12, tb);
  float B[36];
#pragma unroll
  for (int i = 0; i < 10; ++i) B[i] = ta[i];
#pragma unroll
  for (int i = 10; i < 26; ++i) B[i] = fmaxf(ta[i], tb[35 - i]);
#pragma unroll
  for (int i = 26; i < 36; ++i) B[i] = tb[35 - i];
  b36(B);

  // gap columns: cc = t+4 .. t+8
  float G1[16], G2[16];
#pragma unroll
  for (int j = 0; j < 8; ++j) G1[j] = SG[j * COLS + (t + 4)];
#pragma unroll
  for (int j = 0; j < 8; ++j) G1[8 + j] = SG[(7 - j) * COLS + (t + 5)];
  b16(G1);
#pragma unroll
  for (int j = 0; j < 8; ++j) G2[j] = SG[j * COLS + (t + 6)];
#pragma unroll
  for (int j = 0; j < 8; ++j) G2[8 + j] = SG[(7 - j) * COLS + (t + 7)];
  b16(G2);
  float G[32];
#pragma unroll
  for (int j = 0; j < 16; ++j) G[j] = G1[j];
#pragma unroll
  for (int j = 0; j < 16; ++j) G[16 + j] = G2[15 - j];
  b32(G);
  // fold sorted-32 into B (cap 36)
#pragma unroll
  for (int i = 4; i < 36; ++i) B[i] = fmaxf(B[i], G[35 - i]);
  b36(B);
  // fold last gap column (sorted-8) into B (cap 36)
#pragma unroll
  for (int i = 28; i < 36; ++i) B[i] = fmaxf(B[i], SG[(35 - i) * COLS + (t + 8)]);
  b36(B);

  // ---- A-side: full cols dx=-6..-3 (cc = t+0..3) ----
  merge26(SF, t + 0, t + 1, ta);
  merge26(SF, t + 2, t + 3, tb);
  float A[36];
#pragma unroll
  for (int i = 0; i < 10; ++i) A[i] = ta[i];
#pragma unroll
  for (int i = 10; i < 26; ++i) A[i] = fmaxf(ta[i], tb[35 - i]);
#pragma unroll
  for (int i = 26; i < 36; ++i) A[i] = tb[35 - i];
  b36(A);

  // ---- final: 36th largest of union = min_i max(A_i, B_{35-i}) ----
  float mm[36];
#pragma unroll
  for (int i = 0; i < 36; ++i) mm[i] = fmaxf(A[i], B[35 - i]);
#pragma unroll
  for (int i = 0; i < 18; ++i) mm[i] = fminf(mm[i], mm[i + 18]);
#pragma unroll
  for (int i = 0; i < 9; ++i) mm[i] = fminf(mm[i], mm[i + 9]);
#pragma unroll
  for (int i = 0; i < 4; ++i) mm[i] = fminf(mm[i], mm[i + 4]);
  mm[0] = fminf(mm[0], mm[8]);
  mm[0] = fminf(mm[0], fminf(mm[1], fminf(mm[2], mm[3])));

  out[r0 * RDIM + c0 + t] = alpha * mm[0];
}

// ---- host-side faithful port of the reference ALPHA computation ----
static double log_factorial_port(int n_) {
  double n = n_ + 1.0;
  if (n < 9.0) {
    double f = 1.0;
    for (int i = 2; i <= (int)(n + 0.5); ++i) f *= (double)i;
    return log(f);
  }
  return 0.5 * (log(2.0 * M_PI) - log(n)) +
         n * (log(n + 1.0 / (12.0 * n - 1.0 / (10.0 * n))) - 1.0);
}

static double cfar_fun(int k, int n, double t, double pfa) {
  double s = 0.0;
  for (int i = n; i > n - k; --i) s += log((double)i + t);
  return log_factorial_port(n) - log_factorial_port(n - k) - s - log(pfa);
}

static float compute_alpha() {
  double lo = 1.0, hi = 1e32;
  for (int it = 0; it < 300; ++it) {
    double mid = 0.5 * (lo + hi);
    if (cfar_fun(108, 144, mid, 1e-5) > 0.0)
      lo = mid;
    else
      hi = mid;
  }
  return (float)(0.5 * (lo + hi));
}

static const float g_alpha = compute_alpha();

extern "C" void kernel_launch(void* const* d_in, const int* in_sizes, int n_in,
                              void* d_out, int out_size, void* d_ws, size_t ws_size,
                              hipStream_t stream) {
  const float* in = (const float*)d_in[0];
  float* out = (float*)d_out;
  dim3 block(TX, 1);
  dim3 grid(RDIM / TX, VDIM);
  hipLaunchKernelGGL(cfar_os_kernel, grid, block, 0, stream, in, out, g_alpha);
}